// Round 17
// baseline (440.613 us; speedup 1.0000x reference)
//
#include <hip/hip_runtime.h>

#define WAVE 64
#define OW 256    // hidden width
#define LDA1 96   // padded layer-1 K (67 -> 96, zero pad)
#define NCHUNK 64 // edge chunks for the counting sort
#define PBITS 15  // 32768 bins per LDS part (packed 2x16-bit in 64 KB)
#define PBINS (1 << PBITS)
#define NPART 4   // ceil(100000 / 32768)

typedef short bf16x8 __attribute__((ext_vector_type(8)));
typedef float f32x4  __attribute__((ext_vector_type(4)));
typedef float f32x2  __attribute__((ext_vector_type(2)));

__device__ __forceinline__ unsigned short f2bf(float f) {   // RNE fp32 -> bf16
    unsigned int u = __float_as_uint(f);
    u = (u + 0x7FFF + ((u >> 16) & 1)) >> 16;
    return (unsigned short)u;
}
__device__ __forceinline__ float bf2f(unsigned short u) {
    return __uint_as_float(((unsigned int)u) << 16);
}
__device__ __forceinline__ float bflo(unsigned int u) { return __uint_as_float(u << 16); }
__device__ __forceinline__ float bfhi(unsigned int u) { return __uint_as_float(u & 0xFFFF0000u); }
__device__ __forceinline__ unsigned int packbf(float lo, float hi) {
    return (unsigned int)f2bf(lo) | ((unsigned int)f2bf(hi) << 16);
}
__device__ __forceinline__ float lrelu(float x) { return x > 0.0f ? x : 0.01f * x; }

// fp8 (OCP e4m3) helpers: HW cvt, byte k of uint = col 4u+k
__device__ __forceinline__ unsigned int pack4_f8(float v0, float v1, float v2, float v3) {
    int p = __builtin_amdgcn_cvt_pk_fp8_f32(v0, v1, 0, false);   // bytes 0,1
    p = __builtin_amdgcn_cvt_pk_fp8_f32(v2, v3, p, true);        // bytes 2,3
    return (unsigned int)p;
}
__device__ __forceinline__ unsigned char enc1_f8(float v) {
    return (unsigned char)(__builtin_amdgcn_cvt_pk_fp8_f32(v, 0.0f, 0, false) & 0xFF);
}
__device__ __forceinline__ void acc4_f8(float* a, unsigned int u) {
    f32x2 lo = __builtin_amdgcn_cvt_pk_f32_fp8(u, false);        // bytes 0,1
    f32x2 hi = __builtin_amdgcn_cvt_pk_f32_fp8(u, true);         // bytes 2,3
    a[0] += lo.x; a[1] += lo.y; a[2] += hi.x; a[3] += hi.y;
}

// ---------------- prep: h->bf16 padded + h->fp8 + weight pre-pack ----------------

__device__ __forceinline__ void pack_b_body(const float* __restrict__ Ws,
                                            const float* __restrict__ Wn,
                                            unsigned short* __restrict__ Bb,
                                            int KHALF, int KT_HALF, int idx) {
    int e  = idx & 7;
    int l  = (idx >> 3) & 63;
    int nt = (idx >> 9) & 15;
    int kt = idx >> 13;
    int n  = nt * 16 + (l & 15);
    int kh = (kt < KT_HALF ? kt : kt - KT_HALF) * 32 + (l >> 4) * 8 + e;
    const float* W = (kt < KT_HALF) ? Ws : Wn;
    float v = (kh < KHALF) ? W[(size_t)kh * OW + n] : 0.0f;
    Bb[idx] = f2bf(v);
}

__global__ void prep_kernel(const float* __restrict__ h, unsigned int* __restrict__ hb,
                            unsigned int* __restrict__ hb8, int N, int K,
                            const float* __restrict__ W1s, const float* __restrict__ W1n,
                            unsigned short* __restrict__ Bb1,
                            const float* __restrict__ W2s, const float* __restrict__ W2n,
                            unsigned short* __restrict__ Bb2) {
    const int tid = blockIdx.x * blockDim.x + threadIdx.x;
    const int nth = gridDim.x * blockDim.x;

    const int tot_h = N * (LDA1 / 2);
    for (int i = tid; i < tot_h; i += nth) {
        int row = i / (LDA1 / 2);
        int c   = (i - row * (LDA1 / 2)) * 2;
        float v0 = (c     < K) ? h[(size_t)row * K + c]     : 0.0f;
        float v1 = (c + 1 < K) ? h[(size_t)row * K + c + 1] : 0.0f;
        hb[i] = packbf(v0, v1);
    }
    // h -> fp8 [N][96] (uint = 4 cols)
    const int tot8 = N * (LDA1 / 4);
    for (int i = tid; i < tot8; i += nth) {
        int row = i / (LDA1 / 4);
        int c   = (i - row * (LDA1 / 4)) * 4;
        const float* hr = h + (size_t)row * K;
        float v0 = (c     < K) ? hr[c]     : 0.0f;
        float v1 = (c + 1 < K) ? hr[c + 1] : 0.0f;
        float v2 = (c + 2 < K) ? hr[c + 2] : 0.0f;
        float v3 = (c + 3 < K) ? hr[c + 3] : 0.0f;
        hb8[i] = pack4_f8(v0, v1, v2, v3);
    }
    for (int i = tid; i < 2 * 3 * 16 * 64 * 8; i += nth)
        pack_b_body(W1s, W1n, Bb1, K, 3, i);
    for (int i = tid; i < 2 * 8 * 16 * 64 * 8; i += nth)
        pack_b_body(W2s, W2n, Bb2, OW, 8, i);
}

// ---------------- CSR build: LDS-privatized counting sort (no global atomics) ----------------

__global__ __launch_bounds__(512) void hist_kernel(const int* __restrict__ dst, int E, int N,
                                                   unsigned short* __restrict__ hist,
                                                   unsigned short* __restrict__ rank_local) {
    __shared__ unsigned int lcnt[PBINS / 2];      // 64 KB, 2x16-bit packed
    const int c    = blockIdx.x / NPART;
    const int p    = blockIdx.x - c * NPART;
    const int base = p << PBITS;
    const int nb   = (N - base < PBINS) ? (N - base) : PBINS;
    if (nb <= 0) return;
    const int che = (E + NCHUNK - 1) / NCHUNK;
    const int beg = c * che;
    const int end = (beg + che < E) ? (beg + che) : E;

    for (int i = threadIdx.x; i < PBINS / 2; i += 512) lcnt[i] = 0;
    __syncthreads();

    auto proc = [&](int d, int e) {
        d -= base;
        if ((unsigned)d < (unsigned)nb) {
            unsigned int sh  = (d & 1) * 16;
            unsigned int old = atomicAdd(&lcnt[d >> 1], 1u << sh);
            rank_local[e] = (unsigned short)((old >> sh) & 0xFFFFu);   // owner-only store
        }
    };

    if (((beg | end) & 3) == 0) {                 // vector-load path (16B-aligned chunk)
        const int4* dst4 = (const int4*)(dst + beg);
        const int n4 = (end - beg) >> 2;
        for (int i = threadIdx.x; i < n4; i += 512) {
            int4 d = dst4[i];
            int e = beg + 4 * i;
            proc(d.x, e + 0);
            proc(d.y, e + 1);
            proc(d.z, e + 2);
            proc(d.w, e + 3);
        }
    } else {
        for (int e = beg + (int)threadIdx.x; e < end; e += 512)
            proc(dst[e], e);
    }
    __syncthreads();

    unsigned short* hrow = hist + (size_t)c * N + base;
    for (int i = threadIdx.x; i < nb; i += 512) {
        unsigned int v = lcnt[i >> 1];
        hrow[i] = (unsigned short)((v >> ((i & 1) * 16)) & 0xFFFFu);
    }
}

__global__ void chunk_scan_kernel(unsigned short* __restrict__ hist, int* __restrict__ cnt,
                                  int N) {
    int bin = blockIdx.x * blockDim.x + threadIdx.x;
    if (bin >= N) return;
    int s = 0;
#pragma unroll 8
    for (int c = 0; c < NCHUNK; ++c) {
        size_t idx = (size_t)c * N + bin;
        int t = hist[idx];
        hist[idx] = (unsigned short)s;
        s += t;
    }
    cnt[bin] = s;
}

__global__ __launch_bounds__(1024) void scan_blocksum(const int* __restrict__ cnt,
                                                      int* __restrict__ bsum, int n) {
    __shared__ int s[1024];
    int i = blockIdx.x * 1024 + threadIdx.x;
    s[threadIdx.x] = (i < n) ? cnt[i] : 0;
    __syncthreads();
    for (int off = 512; off > 0; off >>= 1) {
        if (threadIdx.x < off) s[threadIdx.x] += s[threadIdx.x + off];
        __syncthreads();
    }
    if (threadIdx.x == 0) bsum[blockIdx.x] = s[0];
}

__global__ __launch_bounds__(128) void scan_offsets(int* __restrict__ bsum, int nb) {
    __shared__ int s[128];
    int v = (threadIdx.x < nb) ? bsum[threadIdx.x] : 0;
    s[threadIdx.x] = v;
    __syncthreads();
    for (int off = 1; off < 128; off <<= 1) {
        int t = (threadIdx.x >= off) ? s[threadIdx.x - off] : 0;
        __syncthreads();
        s[threadIdx.x] += t;
        __syncthreads();
    }
    if (threadIdx.x < nb) bsum[threadIdx.x] = s[threadIdx.x] - v;   // exclusive
}

__global__ __launch_bounds__(1024) void scan_write(const int* __restrict__ cnt,
                                                   const int* __restrict__ boff,
                                                   int* __restrict__ rowptr, int n) {
    __shared__ int s[1024];
    int i = blockIdx.x * 1024 + threadIdx.x;
    int v = (i < n) ? cnt[i] : 0;
    s[threadIdx.x] = v;
    __syncthreads();
    for (int off = 1; off < 1024; off <<= 1) {
        int t = (threadIdx.x >= off) ? s[threadIdx.x - off] : 0;
        __syncthreads();
        s[threadIdx.x] += t;
        __syncthreads();
    }
    if (i < n) rowptr[i + 1] = boff[blockIdx.x] + s[threadIdx.x];
    if (i == 0) rowptr[0] = 0;
}

// atomic-free fill: pos = rowptr[dst] + hist[chunk][dst] + rank_local  (4-edge vectorized reads)
__global__ void fill_kernel(const int* __restrict__ src, const int* __restrict__ dst,
                            const unsigned short* __restrict__ rank_local,
                            const int* __restrict__ rowptr,
                            const unsigned short* __restrict__ hist,
                            int* __restrict__ csr, int E, int N) {
    const int che = (E + NCHUNK - 1) / NCHUNK;
    const int tid = blockIdx.x * blockDim.x + threadIdx.x;
    const int nth = gridDim.x * blockDim.x;

    if ((che & 3) == 0) {                         // 4 consecutive edges share a chunk
        const int e4 = E >> 2;
        const int4* dst4 = (const int4*)dst;
        const int4* src4 = (const int4*)src;
        const ushort4* r4 = (const ushort4*)rank_local;
        for (int i = tid; i < e4; i += nth) {
            int4 d = dst4[i];
            int4 s = src4[i];
            ushort4 r = r4[i];
            const unsigned short* hrow = hist + (size_t)(4 * i / che) * N;
            csr[rowptr[d.x] + (int)hrow[d.x] + (int)r.x] = s.x;
            csr[rowptr[d.y] + (int)hrow[d.y] + (int)r.y] = s.y;
            csr[rowptr[d.z] + (int)hrow[d.z] + (int)r.z] = s.z;
            csr[rowptr[d.w] + (int)hrow[d.w] + (int)r.w] = s.w;
        }
        for (int e = e4 * 4 + tid; e < E; e += nth) {
            int d = dst[e];
            csr[rowptr[d] + (int)hist[(size_t)(e / che) * N + d] + (int)rank_local[e]] = src[e];
        }
    } else {
        for (int e = tid; e < E; e += nth) {
            int d = dst[e];
            csr[rowptr[d] + (int)hist[(size_t)(e / che) * N + d] + (int)rank_local[e]] = src[e];
        }
    }
}

// ---------------- gathers (neighbor MEAN, fp8 sources, atomic-free) ----------------

// layer-2, COLUMN-SPLIT: pass covers 128 of 256 fp8 cols (half-row = 128 B).
// Wave = 4 x 16-lane groups; lane loads uint2 (8 fp8); footprint/pass = 12.8 MB.
__global__ void gather_mean256_f8(const unsigned char* __restrict__ feat,
                                  const int* __restrict__ rowptr, const int* __restrict__ csr,
                                  unsigned int* __restrict__ aggm, int N, int colhalf) {
    const int lane = threadIdx.x & (WAVE - 1);
    const int grp  = lane >> 4;          // 0..3
    const int sub  = lane & 15;          // uint2 slot (8 cols) within half-row
    const int cb   = colhalf * 128;      // byte offset of column half
    int wave = (blockIdx.x * blockDim.x + threadIdx.x) / WAVE;
    int nw   = (gridDim.x * blockDim.x) / WAVE;

    for (int v = wave; v < N; v += nw) {
        const int beg = rowptr[v], deg = rowptr[v + 1] - beg;
        float a[8];
#pragma unroll
        for (int i = 0; i < 8; ++i) a[i] = 0.0f;

        const int noct = deg >> 3;           // 8 edges per iter (4 grp x 2)
        for (int i = 0; i < noct; ++i) {
            int e0 = csr[beg + 8 * i + grp];
            int e1 = csr[beg + 8 * i + 4 + grp];
            uint2 x0 = *(const uint2*)(feat + (size_t)e0 * 256 + cb + sub * 8);
            uint2 x1 = *(const uint2*)(feat + (size_t)e1 * 256 + cb + sub * 8);
            acc4_f8(a + 0, x0.x); acc4_f8(a + 4, x0.y);
            acc4_f8(a + 0, x1.x); acc4_f8(a + 4, x1.y);
        }
        for (int e = (noct << 3) + grp; e < deg; e += 4) {   // tail, per-group
            int s = csr[beg + e];
            uint2 x = *(const uint2*)(feat + (size_t)s * 256 + cb + sub * 8);
            acc4_f8(a + 0, x.x); acc4_f8(a + 4, x.y);
        }
        // combine the 4 groups
#pragma unroll
        for (int i = 0; i < 8; ++i) {
            a[i] += __shfl_xor(a[i], 16);
            a[i] += __shfl_xor(a[i], 32);
        }
        if (grp == 0) {
            float inv = 1.0f / fmaxf((float)deg, 1.0f);
            uint4 o;
            o.x = packbf(a[0] * inv, a[1] * inv);
            o.y = packbf(a[2] * inv, a[3] * inv);
            o.z = packbf(a[4] * inv, a[5] * inv);
            o.w = packbf(a[6] * inv, a[7] * inv);
            *(uint4*)(aggm + (size_t)v * 128 + colhalf * 64 + sub * 4) = o;
        }
    }
}

// layer-1: rows of 96 fp8 (96 B); split-half wave, 24 active lanes/half, uint (4 cols) each
__global__ void gather_mean_pad_f8(const unsigned char* __restrict__ feat,
                                   const int* __restrict__ rowptr, const int* __restrict__ csr,
                                   unsigned int* __restrict__ aggm, int N) {
    const int lane = threadIdx.x & (WAVE - 1);
    const int half = lane >> 5;
    const int sub  = lane & 31;
    const bool act = sub < 24;
    int wave = (blockIdx.x * blockDim.x + threadIdx.x) / WAVE;
    int nw   = (gridDim.x * blockDim.x) / WAVE;

    for (int v = wave; v < N; v += nw) {
        const int beg = rowptr[v], deg = rowptr[v + 1] - beg;
        const int npairs = deg >> 1;
        float a[4] = {0.f, 0.f, 0.f, 0.f};

        int p = 0;
        for (; p + 3 < npairs; p += 4) {
            int i0 = csr[beg + 2 * (p + 0) + half];
            int i1 = csr[beg + 2 * (p + 1) + half];
            int i2 = csr[beg + 2 * (p + 2) + half];
            int i3 = csr[beg + 2 * (p + 3) + half];
            if (act) {
                unsigned int x0 = *(const unsigned int*)(feat + (size_t)i0 * 96 + sub * 4);
                unsigned int x1 = *(const unsigned int*)(feat + (size_t)i1 * 96 + sub * 4);
                unsigned int x2 = *(const unsigned int*)(feat + (size_t)i2 * 96 + sub * 4);
                unsigned int x3 = *(const unsigned int*)(feat + (size_t)i3 * 96 + sub * 4);
                acc4_f8(a, x0); acc4_f8(a, x1); acc4_f8(a, x2); acc4_f8(a, x3);
            }
        }
        for (; p < npairs; ++p) {
            int i0 = csr[beg + 2 * p + half];
            if (act) {
                unsigned int x0 = *(const unsigned int*)(feat + (size_t)i0 * 96 + sub * 4);
                acc4_f8(a, x0);
            }
        }
        if ((deg & 1) && half == 0) {
            int i0 = csr[beg + deg - 1];
            if (act) {
                unsigned int x0 = *(const unsigned int*)(feat + (size_t)i0 * 96 + sub * 4);
                acc4_f8(a, x0);
            }
        }
#pragma unroll
        for (int i = 0; i < 4; ++i) a[i] += __shfl_xor(a[i], 32);

        if (half == 0 && act) {
            float inv = 1.0f / fmaxf((float)deg, 1.0f);
            uint2 o;
            o.x = packbf(a[0] * inv, a[1] * inv);
            o.y = packbf(a[2] * inv, a[3] * inv);
            *(uint2*)(aggm + (size_t)v * 48 + sub * 2) = o;
        }
    }
}

// ---------------- MFMA SAGE GEMM (128-row tile, 256 thr, CHUNK=2 / 32 KB LDS) ----------------
// 4 waves = 2M x 2N; per wave 64 rows x 128 cols = 4x8 mfma_16x16x32 accs.
// Half the blocks of the 64-row tile -> half the B L2-refetch (the measured bound).
template<int KT_HALF, int CHUNK, bool F8OUT>
__global__ __launch_bounds__(256) void sage_mfma(
    const unsigned short* __restrict__ Hs, const unsigned short* __restrict__ Hn, int lda,
    const unsigned short* __restrict__ Bb, const float* __restrict__ bias,
    unsigned short* __restrict__ outb, unsigned char* __restrict__ out8, int M)
{
    constexpr int NT    = 2 * KT_HALF;
    constexpr int NCH   = NT / CHUNK;
    constexpr int CELEM = CHUNK * 16 * 64;           // bf16x8 elems per chunk
    constexpr int CPT   = CELEM / 256;               // per-thread stage count
    __shared__ bf16x8 Bs[CELEM];                     // CHUNK=2 -> 32 KB

    const int t    = threadIdx.x;
    const int lane = t & 63, wid = t >> 6;
    const int wm   = wid >> 1, wn = wid & 1;
    const int brow = blockIdx.x * 128;
    const int lrow = lane & 15, kblk = lane >> 4;

    int rc[4];
#pragma unroll
    for (int rt = 0; rt < 4; ++rt) {
        int r = brow + wm * 64 + rt * 16 + lrow;
        rc[rt] = (r < M) ? r : (M - 1);
    }

    f32x4 acc[4][8];
#pragma unroll
    for (int rt = 0; rt < 4; ++rt)
#pragma unroll
        for (int ct = 0; ct < 8; ++ct) acc[rt][ct] = (f32x4)0.0f;

    for (int ch = 0; ch < NCH; ++ch) {
        // A register prefetch for this chunk (CHUNK x 4 row-frags)
        bf16x8 a[CHUNK][4];
#pragma unroll
        for (int k = 0; k < CHUNK; ++k) {
            int kt = ch * CHUNK + k;
            bool self = kt < KT_HALF;
            int kh = (self ? kt : kt - KT_HALF) * 32 + kblk * 8;
            const unsigned short* srcp = self ? Hs : Hn;
#pragma unroll
            for (int rt = 0; rt < 4; ++rt)
                a[k][rt] = *(const bf16x8*)(srcp + (size_t)rc[rt] * lda + kh);
        }
        // B chunk stage: global -> regs -> LDS (coalesced both sides)
        const bf16x8* gB = (const bf16x8*)Bb + (size_t)ch * CELEM;
        bf16x8 tmp[CPT];
#pragma unroll
        for (int i = 0; i < CPT; ++i) tmp[i] = gB[i * 256 + t];
        __syncthreads();                 // previous chunk's reads complete
#pragma unroll
        for (int i = 0; i < CPT; ++i) Bs[i * 256 + t] = tmp[i];
        __syncthreads();                 // chunk visible to all waves
        // compute: 8 ds_reads feed 32 MFMAs per kt
#pragma unroll
        for (int k = 0; k < CHUNK; ++k) {
            const bf16x8* bp = &Bs[(k * 16 + wn * 8) * 64 + lane];
#pragma unroll
            for (int ct = 0; ct < 8; ++ct) {
                bf16x8 b = bp[ct * 64];
#pragma unroll
                for (int rt = 0; rt < 4; ++rt)
                    acc[rt][ct] = __builtin_amdgcn_mfma_f32_16x16x32_bf16(a[k][rt], b,
                                                                          acc[rt][ct], 0, 0, 0);
            }
        }
    }

    // D layout: col=lane&15, row=(lane>>4)*4+j
#pragma unroll
    for (int rt = 0; rt < 4; ++rt) {
        int rbase = brow + wm * 64 + rt * 16 + kblk * 4;
#pragma unroll
        for (int ct = 0; ct < 8; ++ct) {
            int col = wn * 128 + ct * 16 + lrow;
            float vb = bias[col];
#pragma unroll
            for (int j = 0; j < 4; ++j) {
                int row = rbase + j;
                if (row < M) {
                    float v = lrelu(acc[rt][ct][j] + vb);
                    outb[(size_t)row * OW + col] = f2bf(v);
                    if (F8OUT)
                        out8[(size_t)row * OW + col] = enc1_f8(v);
                }
            }
        }
    }
}

// ---------------- per-graph mean pool + FC (graph_ids sorted) ----------------

__global__ __launch_bounds__(256) void pool_fc_kernel(
    const unsigned short* __restrict__ x, const int* __restrict__ gid,
    const float* __restrict__ Wfc, const float* __restrict__ bfc,
    float* __restrict__ out, int N, int C)
{
    int g = blockIdx.x;
    int lo = 0, hi = N;
    while (lo < hi) { int m = (lo + hi) >> 1; if (gid[m] < g) lo = m + 1; else hi = m; }
    int beg = lo;
    hi = N;
    while (lo < hi) { int m = (lo + hi) >> 1; if (gid[m] <= g) lo = m + 1; else hi = m; }
    int end = lo;

    __shared__ float hg[OW];
    int c = threadIdx.x;
    float s0 = 0.f, s1 = 0.f, s2 = 0.f, s3 = 0.f;
    int r = beg;
    for (; r + 3 < end; r += 4) {
        s0 += bf2f(x[(size_t)(r + 0) * OW + c]);
        s1 += bf2f(x[(size_t)(r + 1) * OW + c]);
        s2 += bf2f(x[(size_t)(r + 2) * OW + c]);
        s3 += bf2f(x[(size_t)(r + 3) * OW + c]);
    }
    for (; r < end; ++r) s0 += bf2f(x[(size_t)r * OW + c]);
    float s = (s0 + s1) + (s2 + s3);
    float inv = (end > beg) ? 1.0f / (float)(end - beg) : 0.0f;
    hg[c] = s * inv;
    __syncthreads();

    if (c < C) {
        float a = bfc[c];
        for (int k = 0; k < OW; ++k)
            a = fmaf(hg[k], Wfc[(size_t)k * C + c], a);
        out[(size_t)g * C + c] = a;
    }
}

extern "C" void kernel_launch(void* const* d_in, const int* in_sizes, int n_in,
                              void* d_out, int out_size, void* d_ws, size_t ws_size,
                              hipStream_t stream) {
    const float* h   = (const float*)d_in[0];
    const float* W1s = (const float*)d_in[1];
    const float* W1n = (const float*)d_in[2];
    const float* b1  = (const float*)d_in[3];
    const float* W2s = (const float*)d_in[4];
    const float* W2n = (const float*)d_in[5];
    const float* b2  = (const float*)d_in[6];
    const float* Wfc = (const float*)d_in[7];
    const float* bfc = (const float*)d_in[8];
    const int*   src = (const int*)d_in[9];
    const int*   dst = (const int*)d_in[10];
    const int*   gid = (const int*)d_in[11];

    const int N  = in_sizes[11];          // 100000
    const int E  = in_sizes[9];           // 1600000
    const int K1 = in_sizes[0] / N;       // 67
    const int NC = in_sizes[8];           // 18
    const int G  = out_size / NC;         // 256

    char* w = (char*)d_ws;
    auto alloc = [&](size_t bytes) { char* p = w; w += (bytes + 255) & ~(size_t)255; return p; };
    unsigned int*   hb     = (unsigned int*)alloc((size_t)N * (LDA1 / 2) * 4);
    unsigned int*   hb8    = (unsigned int*)alloc((size_t)N * LDA1);          // fp8 h
    unsigned int*   agg1b  = (unsigned int*)alloc((size_t)N * (LDA1 / 2) * 4);
    unsigned short* x1b    = (unsigned short*)alloc((size_t)N * OW * 2);
    unsigned char*  x1f8   = (unsigned char*)alloc((size_t)N * OW);           // fp8 x1
    unsigned short* agg2b  = (unsigned short*)alloc((size_t)N * OW * 2);
    int*            rowptr = (int*)alloc((size_t)(N + 1) * 4);
    int*            cnt    = (int*)alloc((size_t)N * 4);
    int*            csr    = (int*)alloc((size_t)E * 4);
    unsigned short* rankl  = (unsigned short*)alloc((size_t)E * 2);
    unsigned short* hist   = (unsigned short*)alloc((size_t)NCHUNK * N * 2);
    int*            bsum   = (int*)alloc(1024 * 4);
    unsigned short* Bb1    = (unsigned short*)alloc((size_t)2 * 3 * 16 * 64 * 8 * 2);
    unsigned short* Bb2    = (unsigned short*)alloc((size_t)2 * 8 * 16 * 64 * 8 * 2);

    float* out = (float*)d_out;
    const int nb = (N + 1023) / 1024;

    // CSR build: LDS counting sort (no global atomics, no memsets needed)
    hist_kernel<<<NCHUNK * NPART, 512, 0, stream>>>(dst, E, N, hist, rankl);
    chunk_scan_kernel<<<(N + 255) / 256, 256, 0, stream>>>(hist, cnt, N);
    scan_blocksum<<<nb, 1024, 0, stream>>>(cnt, bsum, N);
    scan_offsets<<<1, 128, 0, stream>>>(bsum, nb);
    scan_write<<<nb, 1024, 0, stream>>>(cnt, bsum, rowptr, N);
    fill_kernel<<<2048, 256, 0, stream>>>(src, dst, rankl, rowptr, hist, csr, E, N);

    // prep: h->bf16 + h->fp8 + weight packs (pure BW)
    prep_kernel<<<2048, 256, 0, stream>>>(h, hb, hb8, N, K1, W1s, W1n, Bb1, W2s, W2n, Bb2);

    const int gemm_grid = (N + 127) / 128;

    // layer 1: fp8 gather, GEMM emits bf16 x1 + fp8 shadow
    gather_mean_pad_f8<<<4096, 256, 0, stream>>>((const unsigned char*)hb8, rowptr, csr,
                                                 agg1b, N);
    sage_mfma<3, 2, true><<<gemm_grid, 256, 0, stream>>>((const unsigned short*)hb,
                                                         (const unsigned short*)agg1b, LDA1,
                                                         Bb1, b1, x1b, x1f8, N);

    // layer 2: column-split fp8 gather (two half passes), then in-place GEMM
    gather_mean256_f8<<<4096, 256, 0, stream>>>(x1f8, rowptr, csr,
                                                (unsigned int*)agg2b, N, 0);
    gather_mean256_f8<<<4096, 256, 0, stream>>>(x1f8, rowptr, csr,
                                                (unsigned int*)agg2b, N, 1);
    sage_mfma<8, 2, false><<<gemm_grid, 256, 0, stream>>>(x1b, agg2b, OW, Bb2, b2,
                                                          x1b, nullptr, N);

    // per-graph mean pool + classifier
    pool_fc_kernel<<<G, 256, 0, stream>>>(x1b, gid, Wfc, bfc, out, N, NC);
}

// Round 18
// 355.098 us; speedup vs baseline: 1.2408x; 1.2408x over previous
//
#include <hip/hip_runtime.h>

#define WAVE 64
#define OW 256    // hidden width
#define LDA1 96   // padded layer-1 K (67 -> 96, zero pad)
#define NCHUNK 64 // edge chunks for the counting sort
#define PBITS 15  // 32768 bins per LDS part (packed 2x16-bit in 64 KB)
#define PBINS (1 << PBITS)
#define NPART 4   // ceil(100000 / 32768)

typedef short bf16x8 __attribute__((ext_vector_type(8)));
typedef float f32x4  __attribute__((ext_vector_type(4)));
typedef float f32x2  __attribute__((ext_vector_type(2)));

__device__ __forceinline__ unsigned short f2bf(float f) {   // RNE fp32 -> bf16
    unsigned int u = __float_as_uint(f);
    u = (u + 0x7FFF + ((u >> 16) & 1)) >> 16;
    return (unsigned short)u;
}
__device__ __forceinline__ float bf2f(unsigned short u) {
    return __uint_as_float(((unsigned int)u) << 16);
}
__device__ __forceinline__ float bflo(unsigned int u) { return __uint_as_float(u << 16); }
__device__ __forceinline__ float bfhi(unsigned int u) { return __uint_as_float(u & 0xFFFF0000u); }
__device__ __forceinline__ unsigned int packbf(float lo, float hi) {
    return (unsigned int)f2bf(lo) | ((unsigned int)f2bf(hi) << 16);
}
__device__ __forceinline__ float lrelu(float x) { return x > 0.0f ? x : 0.01f * x; }

// fp8 (OCP e4m3) helpers: HW cvt, byte k of uint = col 4u+k
__device__ __forceinline__ unsigned int pack4_f8(float v0, float v1, float v2, float v3) {
    int p = __builtin_amdgcn_cvt_pk_fp8_f32(v0, v1, 0, false);   // bytes 0,1
    p = __builtin_amdgcn_cvt_pk_fp8_f32(v2, v3, p, true);        // bytes 2,3
    return (unsigned int)p;
}
__device__ __forceinline__ unsigned char enc1_f8(float v) {
    return (unsigned char)(__builtin_amdgcn_cvt_pk_fp8_f32(v, 0.0f, 0, false) & 0xFF);
}
__device__ __forceinline__ void acc4_f8(float* a, unsigned int u) {
    f32x2 lo = __builtin_amdgcn_cvt_pk_f32_fp8(u, false);        // bytes 0,1
    f32x2 hi = __builtin_amdgcn_cvt_pk_f32_fp8(u, true);         // bytes 2,3
    a[0] += lo.x; a[1] += lo.y; a[2] += hi.x; a[3] += hi.y;
}

// ---------------- prep: h->bf16 padded + h->fp8 + weight pre-pack ----------------

__device__ __forceinline__ void pack_b_body(const float* __restrict__ Ws,
                                            const float* __restrict__ Wn,
                                            unsigned short* __restrict__ Bb,
                                            int KHALF, int KT_HALF, int idx) {
    int e  = idx & 7;
    int l  = (idx >> 3) & 63;
    int nt = (idx >> 9) & 15;
    int kt = idx >> 13;
    int n  = nt * 16 + (l & 15);
    int kh = (kt < KT_HALF ? kt : kt - KT_HALF) * 32 + (l >> 4) * 8 + e;
    const float* W = (kt < KT_HALF) ? Ws : Wn;
    float v = (kh < KHALF) ? W[(size_t)kh * OW + n] : 0.0f;
    Bb[idx] = f2bf(v);
}

__global__ void prep_kernel(const float* __restrict__ h, unsigned int* __restrict__ hb,
                            unsigned int* __restrict__ hb8, int N, int K,
                            const float* __restrict__ W1s, const float* __restrict__ W1n,
                            unsigned short* __restrict__ Bb1,
                            const float* __restrict__ W2s, const float* __restrict__ W2n,
                            unsigned short* __restrict__ Bb2) {
    const int tid = blockIdx.x * blockDim.x + threadIdx.x;
    const int nth = gridDim.x * blockDim.x;

    const int tot_h = N * (LDA1 / 2);
    for (int i = tid; i < tot_h; i += nth) {
        int row = i / (LDA1 / 2);
        int c   = (i - row * (LDA1 / 2)) * 2;
        float v0 = (c     < K) ? h[(size_t)row * K + c]     : 0.0f;
        float v1 = (c + 1 < K) ? h[(size_t)row * K + c + 1] : 0.0f;
        hb[i] = packbf(v0, v1);
    }
    // h -> fp8 [N][96] (uint = 4 cols)
    const int tot8 = N * (LDA1 / 4);
    for (int i = tid; i < tot8; i += nth) {
        int row = i / (LDA1 / 4);
        int c   = (i - row * (LDA1 / 4)) * 4;
        const float* hr = h + (size_t)row * K;
        float v0 = (c     < K) ? hr[c]     : 0.0f;
        float v1 = (c + 1 < K) ? hr[c + 1] : 0.0f;
        float v2 = (c + 2 < K) ? hr[c + 2] : 0.0f;
        float v3 = (c + 3 < K) ? hr[c + 3] : 0.0f;
        hb8[i] = pack4_f8(v0, v1, v2, v3);
    }
    for (int i = tid; i < 2 * 3 * 16 * 64 * 8; i += nth)
        pack_b_body(W1s, W1n, Bb1, K, 3, i);
    for (int i = tid; i < 2 * 8 * 16 * 64 * 8; i += nth)
        pack_b_body(W2s, W2n, Bb2, OW, 8, i);
}

// ---------------- CSR build: LDS-privatized counting sort (no global atomics) ----------------

__global__ __launch_bounds__(512) void hist_kernel(const int* __restrict__ dst, int E, int N,
                                                   unsigned short* __restrict__ hist,
                                                   unsigned short* __restrict__ rank_local) {
    __shared__ unsigned int lcnt[PBINS / 2];      // 64 KB, 2x16-bit packed
    const int c    = blockIdx.x / NPART;
    const int p    = blockIdx.x - c * NPART;
    const int base = p << PBITS;
    const int nb   = (N - base < PBINS) ? (N - base) : PBINS;
    if (nb <= 0) return;
    const int che = (E + NCHUNK - 1) / NCHUNK;
    const int beg = c * che;
    const int end = (beg + che < E) ? (beg + che) : E;

    for (int i = threadIdx.x; i < PBINS / 2; i += 512) lcnt[i] = 0;
    __syncthreads();

    auto proc = [&](int d, int e) {
        d -= base;
        if ((unsigned)d < (unsigned)nb) {
            unsigned int sh  = (d & 1) * 16;
            unsigned int old = atomicAdd(&lcnt[d >> 1], 1u << sh);
            rank_local[e] = (unsigned short)((old >> sh) & 0xFFFFu);   // owner-only store
        }
    };

    if (((beg | end) & 3) == 0) {                 // vector-load path (16B-aligned chunk)
        const int4* dst4 = (const int4*)(dst + beg);
        const int n4 = (end - beg) >> 2;
        for (int i = threadIdx.x; i < n4; i += 512) {
            int4 d = dst4[i];
            int e = beg + 4 * i;
            proc(d.x, e + 0);
            proc(d.y, e + 1);
            proc(d.z, e + 2);
            proc(d.w, e + 3);
        }
    } else {
        for (int e = beg + (int)threadIdx.x; e < end; e += 512)
            proc(dst[e], e);
    }
    __syncthreads();

    unsigned short* hrow = hist + (size_t)c * N + base;
    for (int i = threadIdx.x; i < nb; i += 512) {
        unsigned int v = lcnt[i >> 1];
        hrow[i] = (unsigned short)((v >> ((i & 1) * 16)) & 0xFFFFu);
    }
}

__global__ void chunk_scan_kernel(unsigned short* __restrict__ hist, int* __restrict__ cnt,
                                  int N) {
    int bin = blockIdx.x * blockDim.x + threadIdx.x;
    if (bin >= N) return;
    int s = 0;
#pragma unroll 8
    for (int c = 0; c < NCHUNK; ++c) {
        size_t idx = (size_t)c * N + bin;
        int t = hist[idx];
        hist[idx] = (unsigned short)s;
        s += t;
    }
    cnt[bin] = s;
}

__global__ __launch_bounds__(1024) void scan_blocksum(const int* __restrict__ cnt,
                                                      int* __restrict__ bsum, int n) {
    __shared__ int s[1024];
    int i = blockIdx.x * 1024 + threadIdx.x;
    s[threadIdx.x] = (i < n) ? cnt[i] : 0;
    __syncthreads();
    for (int off = 512; off > 0; off >>= 1) {
        if (threadIdx.x < off) s[threadIdx.x] += s[threadIdx.x + off];
        __syncthreads();
    }
    if (threadIdx.x == 0) bsum[blockIdx.x] = s[0];
}

__global__ __launch_bounds__(128) void scan_offsets(int* __restrict__ bsum, int nb) {
    __shared__ int s[128];
    int v = (threadIdx.x < nb) ? bsum[threadIdx.x] : 0;
    s[threadIdx.x] = v;
    __syncthreads();
    for (int off = 1; off < 128; off <<= 1) {
        int t = (threadIdx.x >= off) ? s[threadIdx.x - off] : 0;
        __syncthreads();
        s[threadIdx.x] += t;
        __syncthreads();
    }
    if (threadIdx.x < nb) bsum[threadIdx.x] = s[threadIdx.x] - v;   // exclusive
}

__global__ __launch_bounds__(1024) void scan_write(const int* __restrict__ cnt,
                                                   const int* __restrict__ boff,
                                                   int* __restrict__ rowptr, int n) {
    __shared__ int s[1024];
    int i = blockIdx.x * 1024 + threadIdx.x;
    int v = (i < n) ? cnt[i] : 0;
    s[threadIdx.x] = v;
    __syncthreads();
    for (int off = 1; off < 1024; off <<= 1) {
        int t = (threadIdx.x >= off) ? s[threadIdx.x - off] : 0;
        __syncthreads();
        s[threadIdx.x] += t;
        __syncthreads();
    }
    if (i < n) rowptr[i + 1] = boff[blockIdx.x] + s[threadIdx.x];
    if (i == 0) rowptr[0] = 0;
}

// atomic-free fill: pos = rowptr[dst] + hist[chunk][dst] + rank_local  (4-edge vectorized reads)
__global__ void fill_kernel(const int* __restrict__ src, const int* __restrict__ dst,
                            const unsigned short* __restrict__ rank_local,
                            const int* __restrict__ rowptr,
                            const unsigned short* __restrict__ hist,
                            int* __restrict__ csr, int E, int N) {
    const int che = (E + NCHUNK - 1) / NCHUNK;
    const int tid = blockIdx.x * blockDim.x + threadIdx.x;
    const int nth = gridDim.x * blockDim.x;

    if ((che & 3) == 0) {                         // 4 consecutive edges share a chunk
        const int e4 = E >> 2;
        const int4* dst4 = (const int4*)dst;
        const int4* src4 = (const int4*)src;
        const ushort4* r4 = (const ushort4*)rank_local;
        for (int i = tid; i < e4; i += nth) {
            int4 d = dst4[i];
            int4 s = src4[i];
            ushort4 r = r4[i];
            const unsigned short* hrow = hist + (size_t)(4 * i / che) * N;
            csr[rowptr[d.x] + (int)hrow[d.x] + (int)r.x] = s.x;
            csr[rowptr[d.y] + (int)hrow[d.y] + (int)r.y] = s.y;
            csr[rowptr[d.z] + (int)hrow[d.z] + (int)r.z] = s.z;
            csr[rowptr[d.w] + (int)hrow[d.w] + (int)r.w] = s.w;
        }
        for (int e = e4 * 4 + tid; e < E; e += nth) {
            int d = dst[e];
            csr[rowptr[d] + (int)hist[(size_t)(e / che) * N + d] + (int)rank_local[e]] = src[e];
        }
    } else {
        for (int e = tid; e < E; e += nth) {
            int d = dst[e];
            csr[rowptr[d] + (int)hist[(size_t)(e / che) * N + d] + (int)rank_local[e]] = src[e];
        }
    }
}

// ---------------- gathers (neighbor MEAN, fp8 sources, atomic-free) ----------------

// layer-2: rows of 256 fp8 (256 B); wave = 4 x 16-lane groups; lane loads uint4 (16 fp8)
__global__ void gather_mean256_f8(const unsigned char* __restrict__ feat,
                                  const int* __restrict__ rowptr, const int* __restrict__ csr,
                                  unsigned int* __restrict__ aggm, int N) {
    const int lane = threadIdx.x & (WAVE - 1);
    const int grp  = lane >> 4;          // 0..3
    const int sub  = lane & 15;          // uint4 slot (16 cols) within row
    int wave = (blockIdx.x * blockDim.x + threadIdx.x) / WAVE;
    int nw   = (gridDim.x * blockDim.x) / WAVE;

    for (int v = wave; v < N; v += nw) {
        const int beg = rowptr[v], deg = rowptr[v + 1] - beg;
        float a[16];
#pragma unroll
        for (int i = 0; i < 16; ++i) a[i] = 0.0f;

        const int noct = deg >> 3;           // 8 edges per iter (4 grp x 2)
        for (int i = 0; i < noct; ++i) {
            int e0 = csr[beg + 8 * i + grp];
            int e1 = csr[beg + 8 * i + 4 + grp];
            uint4 x0 = *(const uint4*)(feat + (size_t)e0 * 256 + sub * 16);
            uint4 x1 = *(const uint4*)(feat + (size_t)e1 * 256 + sub * 16);
            acc4_f8(a + 0,  x0.x); acc4_f8(a + 4,  x0.y);
            acc4_f8(a + 8,  x0.z); acc4_f8(a + 12, x0.w);
            acc4_f8(a + 0,  x1.x); acc4_f8(a + 4,  x1.y);
            acc4_f8(a + 8,  x1.z); acc4_f8(a + 12, x1.w);
        }
        for (int e = (noct << 3) + grp; e < deg; e += 4) {   // tail, per-group
            int s = csr[beg + e];
            uint4 x = *(const uint4*)(feat + (size_t)s * 256 + sub * 16);
            acc4_f8(a + 0,  x.x); acc4_f8(a + 4,  x.y);
            acc4_f8(a + 8,  x.z); acc4_f8(a + 12, x.w);
        }
        // combine the 4 groups
#pragma unroll
        for (int i = 0; i < 16; ++i) {
            a[i] += __shfl_xor(a[i], 16);
            a[i] += __shfl_xor(a[i], 32);
        }
        if (grp == 0) {
            float inv = 1.0f / fmaxf((float)deg, 1.0f);
            unsigned int o[8];
#pragma unroll
            for (int i = 0; i < 8; ++i)
                o[i] = packbf(a[2 * i] * inv, a[2 * i + 1] * inv);
            unsigned int* dst0 = aggm + (size_t)v * 128 + sub * 8;
            *(uint4*)(dst0)     = make_uint4(o[0], o[1], o[2], o[3]);
            *(uint4*)(dst0 + 4) = make_uint4(o[4], o[5], o[6], o[7]);
        }
    }
}

// layer-1: rows of 96 fp8 (96 B); split-half wave, 24 active lanes/half, uint (4 cols) each
__global__ void gather_mean_pad_f8(const unsigned char* __restrict__ feat,
                                   const int* __restrict__ rowptr, const int* __restrict__ csr,
                                   unsigned int* __restrict__ aggm, int N) {
    const int lane = threadIdx.x & (WAVE - 1);
    const int half = lane >> 5;
    const int sub  = lane & 31;
    const bool act = sub < 24;
    int wave = (blockIdx.x * blockDim.x + threadIdx.x) / WAVE;
    int nw   = (gridDim.x * blockDim.x) / WAVE;

    for (int v = wave; v < N; v += nw) {
        const int beg = rowptr[v], deg = rowptr[v + 1] - beg;
        const int npairs = deg >> 1;
        float a[4] = {0.f, 0.f, 0.f, 0.f};

        int p = 0;
        for (; p + 3 < npairs; p += 4) {
            int i0 = csr[beg + 2 * (p + 0) + half];
            int i1 = csr[beg + 2 * (p + 1) + half];
            int i2 = csr[beg + 2 * (p + 2) + half];
            int i3 = csr[beg + 2 * (p + 3) + half];
            if (act) {
                unsigned int x0 = *(const unsigned int*)(feat + (size_t)i0 * 96 + sub * 4);
                unsigned int x1 = *(const unsigned int*)(feat + (size_t)i1 * 96 + sub * 4);
                unsigned int x2 = *(const unsigned int*)(feat + (size_t)i2 * 96 + sub * 4);
                unsigned int x3 = *(const unsigned int*)(feat + (size_t)i3 * 96 + sub * 4);
                acc4_f8(a, x0); acc4_f8(a, x1); acc4_f8(a, x2); acc4_f8(a, x3);
            }
        }
        for (; p < npairs; ++p) {
            int i0 = csr[beg + 2 * p + half];
            if (act) {
                unsigned int x0 = *(const unsigned int*)(feat + (size_t)i0 * 96 + sub * 4);
                acc4_f8(a, x0);
            }
        }
        if ((deg & 1) && half == 0) {
            int i0 = csr[beg + deg - 1];
            if (act) {
                unsigned int x0 = *(const unsigned int*)(feat + (size_t)i0 * 96 + sub * 4);
                acc4_f8(a, x0);
            }
        }
#pragma unroll
        for (int i = 0; i < 4; ++i) a[i] += __shfl_xor(a[i], 32);

        if (half == 0 && act) {
            float inv = 1.0f / fmaxf((float)deg, 1.0f);
            uint2 o;
            o.x = packbf(a[0] * inv, a[1] * inv);
            o.y = packbf(a[2] * inv, a[3] * inv);
            *(uint2*)(aggm + (size_t)v * 48 + sub * 2) = o;
        }
    }
}

// ---------------- MFMA SAGE GEMM (R16 geometry + next-chunk prefetch) ----------------
// 256 thr = 4 waves (2M x 2N), 64-row tile, CHUNK=2 -> 32 KB LDS (proven best geometry).
// New: chunk ch+1's A+B global loads are issued BETWEEN the second barrier and the MFMAs,
// so their latency hides under compute + the next iteration's barrier/ds_write.
template<int KT_HALF, int CHUNK, bool F8OUT>
__global__ __launch_bounds__(256) void sage_mfma(
    const unsigned short* __restrict__ Hs, const unsigned short* __restrict__ Hn, int lda,
    const unsigned short* __restrict__ Bb, const float* __restrict__ bias,
    unsigned short* __restrict__ outb, unsigned char* __restrict__ out8, int M)
{
    constexpr int NT    = 2 * KT_HALF;
    constexpr int NCH   = NT / CHUNK;
    constexpr int CELEM = CHUNK * 16 * 64;           // bf16x8 elems per chunk
    constexpr int CPT   = CELEM / 256;               // per-thread stage count
    __shared__ bf16x8 Bs[CELEM];                     // CHUNK=2 -> 32 KB

    const int t    = threadIdx.x;
    const int lane = t & 63, wid = t >> 6;
    const int wm   = wid >> 1, wn = wid & 1;
    const int brow = blockIdx.x * 64;
    const int lrow = lane & 15, kblk = lane >> 4;

    const int r0 = brow + wm * 32 + lrow;
    const int r1 = r0 + 16;
    const int r0c = (r0 < M) ? r0 : (M - 1);
    const int r1c = (r1 < M) ? r1 : (M - 1);

    f32x4 acc[2][8];
#pragma unroll
    for (int rt = 0; rt < 2; ++rt)
#pragma unroll
        for (int ct = 0; ct < 8; ++ct) acc[rt][ct] = (f32x4)0.0f;

    auto loadA = [&](int ch, bf16x8 (&a0)[CHUNK], bf16x8 (&a1)[CHUNK]) {
#pragma unroll
        for (int k = 0; k < CHUNK; ++k) {
            int kt = ch * CHUNK + k;
            bool self = kt < KT_HALF;
            int kh = (self ? kt : kt - KT_HALF) * 32 + kblk * 8;
            const unsigned short* srcp = self ? Hs : Hn;
            a0[k] = *(const bf16x8*)(srcp + (size_t)r0c * lda + kh);
            a1[k] = *(const bf16x8*)(srcp + (size_t)r1c * lda + kh);
        }
    };

    const bf16x8* gB = (const bf16x8*)Bb;
    bf16x8 tmpB[CPT];
    bf16x8 a0[CHUNK], a1[CHUNK];
#pragma unroll
    for (int i = 0; i < CPT; ++i) tmpB[i] = gB[i * 256 + t];
    loadA(0, a0, a1);

#pragma unroll
    for (int ch = 0; ch < NCH; ++ch) {
        __syncthreads();                 // Bs free (previous chunk's reads done)
#pragma unroll
        for (int i = 0; i < CPT; ++i) Bs[i * 256 + t] = tmpB[i];   // waits on tmpB loads
        __syncthreads();                 // chunk visible to all waves

        bf16x8 nB[CPT], n0[CHUNK], n1[CHUNK];
        if (ch + 1 < NCH) {              // issue next-chunk loads; latency hides under MFMAs
            const bf16x8* g = gB + (size_t)(ch + 1) * CELEM;
#pragma unroll
            for (int i = 0; i < CPT; ++i) nB[i] = g[i * 256 + t];
            loadA(ch + 1, n0, n1);
        }

#pragma unroll
        for (int k = 0; k < CHUNK; ++k) {
            const bf16x8* bp = &Bs[(k * 16 + wn * 8) * 64 + lane];
#pragma unroll
            for (int ct = 0; ct < 8; ++ct) {
                bf16x8 b = bp[ct * 64];
                acc[0][ct] = __builtin_amdgcn_mfma_f32_16x16x32_bf16(a0[k], b, acc[0][ct], 0, 0, 0);
                acc[1][ct] = __builtin_amdgcn_mfma_f32_16x16x32_bf16(a1[k], b, acc[1][ct], 0, 0, 0);
            }
        }
        if (ch + 1 < NCH) {
#pragma unroll
            for (int i = 0; i < CPT; ++i) tmpB[i] = nB[i];
#pragma unroll
            for (int k = 0; k < CHUNK; ++k) { a0[k] = n0[k]; a1[k] = n1[k]; }
        }
    }

    // D layout: col=lane&15, row=(lane>>4)*4+j
#pragma unroll
    for (int rt = 0; rt < 2; ++rt) {
        int rbase = brow + wm * 32 + rt * 16 + kblk * 4;
#pragma unroll
        for (int ct = 0; ct < 8; ++ct) {
            int col = wn * 128 + ct * 16 + lrow;
            float vb = bias[col];
#pragma unroll
            for (int j = 0; j < 4; ++j) {
                int row = rbase + j;
                if (row < M) {
                    float v = lrelu(acc[rt][ct][j] + vb);
                    outb[(size_t)row * OW + col] = f2bf(v);
                    if (F8OUT)
                        out8[(size_t)row * OW + col] = enc1_f8(v);
                }
            }
        }
    }
}

// ---------------- per-graph mean pool + FC (graph_ids sorted) ----------------

__global__ __launch_bounds__(256) void pool_fc_kernel(
    const unsigned short* __restrict__ x, const int* __restrict__ gid,
    const float* __restrict__ Wfc, const float* __restrict__ bfc,
    float* __restrict__ out, int N, int C)
{
    int g = blockIdx.x;
    int lo = 0, hi = N;
    while (lo < hi) { int m = (lo + hi) >> 1; if (gid[m] < g) lo = m + 1; else hi = m; }
    int beg = lo;
    hi = N;
    while (lo < hi) { int m = (lo + hi) >> 1; if (gid[m] <= g) lo = m + 1; else hi = m; }
    int end = lo;

    __shared__ float hg[OW];
    int c = threadIdx.x;
    float s0 = 0.f, s1 = 0.f, s2 = 0.f, s3 = 0.f;
    int r = beg;
    for (; r + 3 < end; r += 4) {
        s0 += bf2f(x[(size_t)(r + 0) * OW + c]);
        s1 += bf2f(x[(size_t)(r + 1) * OW + c]);
        s2 += bf2f(x[(size_t)(r + 2) * OW + c]);
        s3 += bf2f(x[(size_t)(r + 3) * OW + c]);
    }
    for (; r < end; ++r) s0 += bf2f(x[(size_t)r * OW + c]);
    float s = (s0 + s1) + (s2 + s3);
    float inv = (end > beg) ? 1.0f / (float)(end - beg) : 0.0f;
    hg[c] = s * inv;
    __syncthreads();

    if (c < C) {
        float a = bfc[c];
        for (int k = 0; k < OW; ++k)
            a = fmaf(hg[k], Wfc[(size_t)k * C + c], a);
        out[(size_t)g * C + c] = a;
    }
}

extern "C" void kernel_launch(void* const* d_in, const int* in_sizes, int n_in,
                              void* d_out, int out_size, void* d_ws, size_t ws_size,
                              hipStream_t stream) {
    const float* h   = (const float*)d_in[0];
    const float* W1s = (const float*)d_in[1];
    const float* W1n = (const float*)d_in[2];
    const float* b1  = (const float*)d_in[3];
    const float* W2s = (const float*)d_in[4];
    const float* W2n = (const float*)d_in[5];
    const float* b2  = (const float*)d_in[6];
    const float* Wfc = (const float*)d_in[7];
    const float* bfc = (const float*)d_in[8];
    const int*   src = (const int*)d_in[9];
    const int*   dst = (const int*)d_in[10];
    const int*   gid = (const int*)d_in[11];

    const int N  = in_sizes[11];          // 100000
    const int E  = in_sizes[9];           // 1600000
    const int K1 = in_sizes[0] / N;       // 67
    const int NC = in_sizes[8];           // 18
    const int G  = out_size / NC;         // 256

    char* w = (char*)d_ws;
    auto alloc = [&](size_t bytes) { char* p = w; w += (bytes + 255) & ~(size_t)255; return p; };
    unsigned int*   hb     = (unsigned int*)alloc((size_t)N * (LDA1 / 2) * 4);
    unsigned int*   hb8    = (unsigned int*)alloc((size_t)N * LDA1);          // fp8 h
    unsigned int*   agg1b  = (unsigned int*)alloc((size_t)N * (LDA1 / 2) * 4);
    unsigned short* x1b    = (unsigned short*)alloc((size_t)N * OW * 2);
    unsigned char*  x1f8   = (unsigned char*)alloc((size_t)N * OW);           // fp8 x1
    unsigned short* agg2b  = (unsigned short*)alloc((size_t)N * OW * 2);
    int*            rowptr = (int*)alloc((size_t)(N + 1) * 4);
    int*            cnt    = (int*)alloc((size_t)N * 4);
    int*            csr    = (int*)alloc((size_t)E * 4);
    unsigned short* rankl  = (unsigned short*)alloc((size_t)E * 2);
    unsigned short* hist   = (unsigned short*)alloc((size_t)NCHUNK * N * 2);
    int*            bsum   = (int*)alloc(1024 * 4);
    unsigned short* Bb1    = (unsigned short*)alloc((size_t)2 * 3 * 16 * 64 * 8 * 2);
    unsigned short* Bb2    = (unsigned short*)alloc((size_t)2 * 8 * 16 * 64 * 8 * 2);

    float* out = (float*)d_out;
    const int nb = (N + 1023) / 1024;

    // CSR build: LDS counting sort (no global atomics, no memsets needed)
    hist_kernel<<<NCHUNK * NPART, 512, 0, stream>>>(dst, E, N, hist, rankl);
    chunk_scan_kernel<<<(N + 255) / 256, 256, 0, stream>>>(hist, cnt, N);
    scan_blocksum<<<nb, 1024, 0, stream>>>(cnt, bsum, N);
    scan_offsets<<<1, 128, 0, stream>>>(bsum, nb);
    scan_write<<<nb, 1024, 0, stream>>>(cnt, bsum, rowptr, N);
    fill_kernel<<<2048, 256, 0, stream>>>(src, dst, rankl, rowptr, hist, csr, E, N);

    // prep: h->bf16 + h->fp8 + weight packs (pure BW)
    prep_kernel<<<2048, 256, 0, stream>>>(h, hb, hb8, N, K1, W1s, W1n, Bb1, W2s, W2n, Bb2);

    const int gemm_grid = (N + 63) / 64;

    // layer 1: fp8 gather, GEMM emits bf16 x1 + fp8 shadow
    gather_mean_pad_f8<<<4096, 256, 0, stream>>>((const unsigned char*)hb8, rowptr, csr,
                                                 agg1b, N);
    sage_mfma<3, 2, true><<<gemm_grid, 256, 0, stream>>>((const unsigned short*)hb,
                                                         (const unsigned short*)agg1b, LDA1,
                                                         Bb1, b1, x1b, x1f8, N);

    // layer 2: single-pass fp8 gather, then in-place GEMM
    gather_mean256_f8<<<4096, 256, 0, stream>>>(x1f8, rowptr, csr,
                                                (unsigned int*)agg2b, N);
    sage_mfma<8, 2, false><<<gemm_grid, 256, 0, stream>>>(x1b, agg2b, OW, Bb2, b2,
                                                          x1b, nullptr, N);

    // per-graph mean pool + classifier
    pool_fc_kernel<<<G, 256, 0, stream>>>(x1b, gid, Wfc, bfc, out, N, NC);
}